// Round 11
// baseline (748.041 us; speedup 1.0000x reference)
//
#include <hip/hip_runtime.h>
#include <hip/hip_bf16.h>

#define N_NODES 50000
#define N_EDGES 800000
#define NODE_DIM 256
#define EDGE_DIM 64
#define NUM_REL 4
#define HID 512
#define LAST 128
#define BATCH 16384
#define EPS 1e-10f
#define NSEG (N_NODES * NUM_REL)

#define K1 1600   // meanX 1024 | E1 256 | x 256 | f 4 | pad 60
#define K2 832    // E1 256 | h1 512 | f 4 | pad 60

typedef __bf16 bf16_t;
typedef __attribute__((ext_vector_type(8))) __bf16 bf16x8;
typedef __attribute__((ext_vector_type(4))) __bf16 bf16x4;
typedef __attribute__((ext_vector_type(2))) __bf16 bf16x2;
typedef __attribute__((ext_vector_type(4))) float f32x4;

typedef __attribute__((address_space(1))) const unsigned int g_u32;
typedef __attribute__((address_space(3))) unsigned int l_u32;
static __device__ __forceinline__ void gload16(const void* g, void* l) {
    __builtin_amdgcn_global_load_lds((g_u32*)g, (l_u32*)l, 16, 0, 0);
}

// ================= CSR build =================
__global__ __launch_bounds__(256) void hist_kernel(
    const int* __restrict__ edst, const int* __restrict__ erel, int* __restrict__ hist)
{
    int e = blockIdx.x * 256 + threadIdx.x;
    if (e >= N_EDGES) return;
    atomicAdd(&hist[edst[e] * NUM_REL + erel[e]], 1);
}

#define SCAN_B 2048
__global__ __launch_bounds__(256) void scan1(
    const int* __restrict__ in, int* __restrict__ out, int* __restrict__ bsum, int n)
{
    __shared__ int sh[256];
    int base = blockIdx.x * SCAN_B + threadIdx.x * 8;
    int v[8]; int s = 0;
#pragma unroll
    for (int i = 0; i < 8; ++i) {
        int idx = base + i;
        v[i] = s;
        s += (idx < n) ? in[idx] : 0;
    }
    sh[threadIdx.x] = s;
    __syncthreads();
    for (int off = 1; off < 256; off <<= 1) {
        int t = (threadIdx.x >= off) ? sh[threadIdx.x - off] : 0;
        __syncthreads();
        sh[threadIdx.x] += t;
        __syncthreads();
    }
    int texcl = (threadIdx.x == 0) ? 0 : sh[threadIdx.x - 1];
#pragma unroll
    for (int i = 0; i < 8; ++i) {
        int idx = base + i;
        if (idx < n) out[idx] = texcl + v[i];
    }
    if (threadIdx.x == 255) bsum[blockIdx.x] = sh[255];
}

__global__ void scan2(int* bsum, int nb)
{
    if (threadIdx.x == 0 && blockIdx.x == 0) {
        int s = 0;
        for (int i = 0; i < nb; ++i) { int t = bsum[i]; bsum[i] = s; s += t; }
    }
}

// writes final offsets AND initializes cursor to the same value
__global__ __launch_bounds__(256) void scan3(int* __restrict__ out, int* __restrict__ cursor,
                                             const int* __restrict__ bsum, int n)
{
    int idx = blockIdx.x * SCAN_B + threadIdx.x * 8;
    int add = bsum[blockIdx.x];
#pragma unroll
    for (int i = 0; i < 8; ++i)
        if (idx + i < n) {
            int v = out[idx + i] + add;
            out[idx + i] = v;
            cursor[idx + i] = v;
        }
}

__global__ __launch_bounds__(256) void csr_fill(
    const int* __restrict__ edst, const int* __restrict__ erel, const int* __restrict__ esrc,
    int* __restrict__ cursor,
    int* __restrict__ csr_src, int* __restrict__ csr_eid)
{
    int e = blockIdx.x * 256 + threadIdx.x;
    if (e >= N_EDGES) return;
    int seg = edst[e] * NUM_REL + erel[e];
    int pos = atomicAdd(&cursor[seg], 1);
    csr_src[pos] = esrc[e];
    csr_eid[pos] = e;
}

// ================= small converts, fused =================
__global__ __launch_bounds__(256) void prep_small(
    const float* __restrict__ Wc1, const float* __restrict__ Wc2,
    const float* __restrict__ Wf1, const float* __restrict__ Wf2,
    const float* __restrict__ bl1, const float* __restrict__ bs1,
    const float* __restrict__ bl2, const float* __restrict__ bs2,
    bf16_t* __restrict__ Wc1b, bf16_t* __restrict__ Wc2b,
    bf16_t* __restrict__ Wf1b, bf16_t* __restrict__ Wf2b,
    float* __restrict__ bias12, float* __restrict__ bias22)
{
    int i = blockIdx.x * 256 + threadIdx.x;
    const float* src; bf16_t* dst; int base;
    if (i < 4096)        { src = Wc1; dst = Wc1b; base = 0; }
    else if (i < 12288)  { src = Wc2; dst = Wc2b; base = 4096; }
    else if (i < 24576)  { src = Wf1; dst = Wf1b; base = 12288; }
    else if (i < 26624)  { src = Wf2; dst = Wf2b; base = 24576; }
    else {
        int j = i - 26624;
        if (j < 512) bias12[j] = bl1[j] + bs1[j];
        else if (j < 640) bias22[j - 512] = bl2[j - 512] + bs2[j - 512];
        return;
    }
    int k = i - base;
    float4 v = ((const float4*)src)[k];
    bf16x4 o;
    o[0] = (bf16_t)v.x; o[1] = (bf16_t)v.y; o[2] = (bf16_t)v.z; o[3] = (bf16_t)v.w;
    ((bf16x4*)dst)[k] = o;
}

// x (fp32 [50000,256]) -> A1 cols 1280..1535 (bf16) AND compact xb [50000,256]
__global__ __launch_bounds__(256) void xconv_k(const float* __restrict__ x, bf16_t* __restrict__ A1,
                                               bf16_t* __restrict__ xb)
{
    int i = blockIdx.x * 256 + threadIdx.x;   // over 50000*64
    int n = i >> 6;
    int c4 = i & 63;
    float4 v = ((const float4*)(x + (size_t)n * 256))[c4];
    bf16x4 o;
    o[0] = (bf16_t)v.x; o[1] = (bf16_t)v.y; o[2] = (bf16_t)v.z; o[3] = (bf16_t)v.w;
    *(bf16x4*)(A1 + (size_t)n * K1 + 1280 + c4 * 4) = o;
    *(bf16x4*)(xb + (size_t)n * 256 + c4 * 4) = o;
}

// ================= weight prep =================
__global__ __launch_bounds__(256) void prep_w1cat(
    const float* __restrict__ Wl1, const float* __restrict__ We1,
    const float* __restrict__ Ws1, const float* __restrict__ be1, bf16_t* __restrict__ W1cat)
{
    int j = blockIdx.x;
    int t = threadIdx.x;
    const float* wrow = Wl1 + (size_t)j * 1024;
    bf16_t* out = W1cat + (size_t)j * K1;
    for (int c = t; c < 1024; c += 256) out[c] = (bf16_t)wrow[c];
    {
        int r = t >> 6, e = t & 63;
        float s = 0.f;
        const float* wr = wrow + r * 256;
        for (int c = 0; c < 256; ++c) s += wr[c] * We1[c * 64 + e];
        out[1024 + t] = (bf16_t)s;
    }
    if (t < 256) out[1280 + t] = (bf16_t)Ws1[(size_t)j * 256 + t];
    if (t < 4) {
        float s = 0.f;
        const float* wr = wrow + t * 256;
        for (int c = 0; c < 256; ++c) s += wr[c] * be1[c];
        out[1536 + t] = (bf16_t)s;
    }
    if (t >= 4 && t < 64) out[1536 + t] = (bf16_t)0.f;   // pad to K1=1600
}

__global__ __launch_bounds__(256) void prep_w2cat(
    const float* __restrict__ Wl2, const float* __restrict__ We2,
    const float* __restrict__ Ws2, const float* __restrict__ be2, bf16_t* __restrict__ W2cat)
{
    int j = blockIdx.x;
    int t = threadIdx.x;
    const float* wrow = Wl2 + (size_t)j * 2048;
    bf16_t* out = W2cat + (size_t)j * K2;
    {
        int r = t >> 6, e = t & 63;
        float s = 0.f;
        const float* wr = wrow + r * 512;
        for (int k = 0; k < 512; ++k) s += wr[k] * We2[k * 64 + e];
        out[t] = (bf16_t)s;
    }
    for (int c = t; c < 512; c += 256) out[256 + c] = (bf16_t)Ws2[(size_t)j * 512 + c];
    if (t < 4) {
        float s = 0.f;
        const float* wr = wrow + t * 512;
        for (int k = 0; k < 512; ++k) s += wr[k] * be2[k];
        out[768 + t] = (bf16_t)s;
    }
    if (t >= 4 && t < 64) out[768 + t] = (bf16_t)0.f;    // pad to K2=832
}

__global__ __launch_bounds__(256) void prep_w2p(const float* __restrict__ Wl2, bf16_t* __restrict__ W2p)
{
    int idx = blockIdx.x * 256 + threadIdx.x;    // 512*512
    int row = idx >> 9, k = idx & 511;
    int j = row & 127, r = row >> 7;
    W2p[idx] = (bf16_t)Wl2[(size_t)j * 2048 + r * 512 + k];
}

// ================= aggregation =================
// block = node n; wave = relation r; paired-edge lanes (half h -> edge i+h).
__global__ __launch_bounds__(256) void agg1(
    const float* __restrict__ ef, const bf16_t* __restrict__ xb,
    const int* __restrict__ csr_src, const int* __restrict__ csr_eid,
    const int* __restrict__ offs, const int* __restrict__ hist,
    bf16_t* __restrict__ A1, bf16_t* __restrict__ A2)
{
    int n = blockIdx.x;
    int w = threadIdx.x >> 6;
    int lane = threadIdx.x & 63;
    int half = lane >> 5;
    int l32 = lane & 31;
    int seg = n * NUM_REL + w;
    int beg = offs[seg], ct = hist[seg];

    float xs[8] = {0.f, 0.f, 0.f, 0.f, 0.f, 0.f, 0.f, 0.f};
    float es0 = 0.f, es1 = 0.f;

    int i = 0;
    for (; i + 4 <= ct; i += 4) {
        int sA = csr_src[beg + i + half];
        int sB = csr_src[beg + i + 2 + half];
        int eA = csr_eid[beg + i + half];
        int eB = csr_eid[beg + i + 2 + half];
        bf16x8 vA = *(const bf16x8*)(xb + (size_t)sA * 256 + l32 * 8);
        bf16x8 vB = *(const bf16x8*)(xb + (size_t)sB * 256 + l32 * 8);
        float2 fA = *(const float2*)(ef + (size_t)eA * 64 + l32 * 2);
        float2 fB = *(const float2*)(ef + (size_t)eB * 64 + l32 * 2);
#pragma unroll
        for (int j = 0; j < 8; ++j) xs[j] += (float)vA[j] + (float)vB[j];
        es0 += fA.x + fB.x;
        es1 += fA.y + fB.y;
    }
    for (; i + 2 <= ct; i += 2) {
        int sA = csr_src[beg + i + half];
        int eA = csr_eid[beg + i + half];
        bf16x8 vA = *(const bf16x8*)(xb + (size_t)sA * 256 + l32 * 8);
        float2 fA = *(const float2*)(ef + (size_t)eA * 64 + l32 * 2);
#pragma unroll
        for (int j = 0; j < 8; ++j) xs[j] += (float)vA[j];
        es0 += fA.x;
        es1 += fA.y;
    }
    if (i < ct && half == 0) {
        int sA = csr_src[beg + i];
        int eA = csr_eid[beg + i];
        bf16x8 vA = *(const bf16x8*)(xb + (size_t)sA * 256 + l32 * 8);
        float2 fA = *(const float2*)(ef + (size_t)eA * 64 + l32 * 2);
#pragma unroll
        for (int j = 0; j < 8; ++j) xs[j] += (float)vA[j];
        es0 += fA.x;
        es1 += fA.y;
    }
#pragma unroll
    for (int j = 0; j < 8; ++j) xs[j] += __shfl_xor(xs[j], 32);
    es0 += __shfl_xor(es0, 32);
    es1 += __shfl_xor(es1, 32);

    float inv = 1.0f / ((float)ct + EPS);
    if (half == 0) {
        bf16x8 m;
#pragma unroll
        for (int j = 0; j < 8; ++j) m[j] = (bf16_t)(xs[j] * inv);
        *(bf16x8*)(A1 + (size_t)n * K1 + w * 256 + l32 * 8) = m;
        bf16x2 e2;
        e2[0] = (bf16_t)(es0 * inv);
        e2[1] = (bf16_t)(es1 * inv);
        *(bf16x2*)(A1 + (size_t)n * K1 + 1024 + w * 64 + l32 * 2) = e2;
        *(bf16x2*)(A2 + (size_t)n * K2 + w * 64 + l32 * 2) = e2;
    }
    if (lane == 0) {
        bf16_t fv = (bf16_t)((float)ct * inv);
        A1[(size_t)n * K1 + 1536 + w] = fv;
        A2[(size_t)n * K2 + 768 + w] = fv;
    }
    if (w == 3 && lane >= 4) {
        A1[(size_t)n * K1 + 1536 + lane] = (bf16_t)0.f;   // 1540..1599
        A2[(size_t)n * K2 + 768 + lane] = (bf16_t)0.f;    // 772..831
    }
}

__global__ __launch_bounds__(256) void agg2(
    const bf16_t* __restrict__ P, const int* __restrict__ csr_src,
    const int* __restrict__ offs, const int* __restrict__ hist,
    float* __restrict__ h2base)
{
    __shared__ float red[4][128];
    int n = blockIdx.x;
    int w = threadIdx.x >> 6;
    int lane = threadIdx.x & 63;
    int half = lane >> 5;
    int l32 = lane & 31;
    int seg = n * NUM_REL + w;
    int beg = offs[seg], ct = hist[seg];

    float s0 = 0.f, s1 = 0.f, s2 = 0.f, s3 = 0.f;
    int i = 0;
    for (; i + 4 <= ct; i += 4) {
        int a = csr_src[beg + i + half];
        int b = csr_src[beg + i + 2 + half];
        bf16x4 va = *(const bf16x4*)(P + (size_t)a * HID + w * 128 + l32 * 4);
        bf16x4 vb = *(const bf16x4*)(P + (size_t)b * HID + w * 128 + l32 * 4);
        s0 += (float)va[0] + (float)vb[0];
        s1 += (float)va[1] + (float)vb[1];
        s2 += (float)va[2] + (float)vb[2];
        s3 += (float)va[3] + (float)vb[3];
    }
    for (; i + 2 <= ct; i += 2) {
        int a = csr_src[beg + i + half];
        bf16x4 va = *(const bf16x4*)(P + (size_t)a * HID + w * 128 + l32 * 4);
        s0 += (float)va[0]; s1 += (float)va[1]; s2 += (float)va[2]; s3 += (float)va[3];
    }
    if (i < ct && half == 0) {
        int a = csr_src[beg + i];
        bf16x4 va = *(const bf16x4*)(P + (size_t)a * HID + w * 128 + l32 * 4);
        s0 += (float)va[0]; s1 += (float)va[1]; s2 += (float)va[2]; s3 += (float)va[3];
    }
    s0 += __shfl_xor(s0, 32);
    s1 += __shfl_xor(s1, 32);
    s2 += __shfl_xor(s2, 32);
    s3 += __shfl_xor(s3, 32);

    float inv = 1.0f / ((float)ct + EPS);
    if (half == 0) {
        red[w][l32 * 4 + 0] = s0 * inv;
        red[w][l32 * 4 + 1] = s1 * inv;
        red[w][l32 * 4 + 2] = s2 * inv;
        red[w][l32 * 4 + 3] = s3 * inv;
    }
    __syncthreads();
    int t = threadIdx.x;
    if (t < 128)
        h2base[(size_t)n * 128 + t] = red[0][t] + red[1][t] + red[2][t] + red[3][t];
}

// ================= bf16 MFMA GEMM (m97 structure: BK=32, 16KB LDS, 2 barriers,
// XCD-chunked bijective remap, 4-slot XOR swizzle via pre-swizzled global src) ==
// Staging: wave wv instr q in {0,1}: rows (wv*2+q)*16 + (lane>>2); lane stores
// global chunk ((lane&3)^((lane>>3)&3)) at LDS slot (lane&3). Read slot for
// global chunk kch of row r: kch ^ ((r&15)>>1 & 3). Rows are 64B; <=2-way = free.
template<int RELU, int ACC, int OUTBF>
__global__ __launch_bounds__(256) void gemm_bf16(
    const bf16_t* __restrict__ A, int lda,
    const bf16_t* __restrict__ W, int ldw,
    const float* __restrict__ Cin, int ldcin,
    const float* __restrict__ bias,
    void* __restrict__ Cout, int ldc,
    int M, int N, int K, int ncol)
{
    __shared__ char smem[16384];   // As 8KB | Bs 8KB
    const int tid = threadIdx.x;

    const int nwg = gridDim.x;
    const int q8 = nwg >> 3, r8 = nwg & 7;
    const int xcd = blockIdx.x & 7, li = blockIdx.x >> 3;
    const int wgid = (xcd < r8 ? xcd * (q8 + 1) : r8 * (q8 + 1) + (xcd - r8) * q8) + li;

    const int row0 = (wgid / ncol) * 128;
    const int col0 = (wgid % ncol) * 128;
    const int lane = tid & 63, wv = tid >> 6;

    const int srow = lane >> 2;                      // 0..15 within 16-row group
    const int gchunk = (lane & 3) ^ ((lane >> 3) & 3);
    const bf16_t *pa0, *pa1, *pb0, *pb1;
    {
        int r0 = (wv * 2 + 0) * 16 + srow;
        int r1 = (wv * 2 + 1) * 16 + srow;
        int a0 = row0 + r0; if (a0 >= M) a0 = M - 1;
        int a1 = row0 + r1; if (a1 >= M) a1 = M - 1;
        int b0 = col0 + r0; if (b0 >= N) b0 = N - 1;
        int b1 = col0 + r1; if (b1 >= N) b1 = N - 1;
        pa0 = A + (size_t)a0 * lda + gchunk * 8;
        pa1 = A + (size_t)a1 * lda + gchunk * 8;
        pb0 = W + (size_t)b0 * ldw + gchunk * 8;
        pb1 = W + (size_t)b1 * ldw + gchunk * 8;
    }
    char* As = smem;
    char* Bs = smem + 8192;
    char* lA0 = As + (wv * 2 + 0) * 1024;
    char* lA1 = As + (wv * 2 + 1) * 1024;
    char* lB0 = Bs + (wv * 2 + 0) * 1024;
    char* lB1 = Bs + (wv * 2 + 1) * 1024;

    const int wm = wv >> 1, wn = wv & 1;
    const int r16 = lane & 15, kch = lane >> 4;      // kch 0..3
    const int slot = (kch ^ ((r16 >> 1) & 3)) << 4;

    f32x4 acc[4][4];
#pragma unroll
    for (int i = 0; i < 4; ++i)
#pragma unroll
        for (int j = 0; j < 4; ++j) acc[i][j] = (f32x4){0.f, 0.f, 0.f, 0.f};

    for (int k0 = 0; k0 < K; k0 += 32) {
        gload16(pa0 + k0, lA0);
        gload16(pa1 + k0, lA1);
        gload16(pb0 + k0, lB0);
        gload16(pb1 + k0, lB1);
        __syncthreads();
        bf16x8 af[4], bfm[4];
#pragma unroll
        for (int i = 0; i < 4; ++i)
            af[i] = *(const bf16x8*)(As + (wm * 64 + i * 16 + r16) * 64 + slot);
#pragma unroll
        for (int j = 0; j < 4; ++j)
            bfm[j] = *(const bf16x8*)(Bs + (wn * 64 + j * 16 + r16) * 64 + slot);
#pragma unroll
        for (int i = 0; i < 4; ++i)
#pragma unroll
            for (int j = 0; j < 4; ++j)
                acc[i][j] = __builtin_amdgcn_mfma_f32_16x16x32_bf16(af[i], bfm[j], acc[i][j], 0, 0, 0);
        __syncthreads();
    }

    const int crow0 = row0 + wm * 64;
#pragma unroll
    for (int i = 0; i < 4; ++i) {
#pragma unroll
        for (int j = 0; j < 4; ++j) {
            int col = col0 + wn * 64 + j * 16 + r16;
            if (col >= N) continue;
            float bv = bias ? bias[col] : 0.f;
#pragma unroll
            for (int q = 0; q < 4; ++q) {
                int row = crow0 + i * 16 + kch * 4 + q;
                if (row >= M) continue;
                float v = acc[i][j][q] + bv;
                if (ACC) v += Cin[(size_t)row * ldcin + col];
                if (RELU) v = fmaxf(v, 0.f);
                if (OUTBF) ((bf16_t*)Cout)[(size_t)row * ldc + col] = (bf16_t)v;
                else       ((float*)Cout)[(size_t)row * ldc + col] = v;
            }
        }
    }
}

// ======== gathered-A f1 GEMM: f1 = relu([h2[d1]|h2[d2]|x3] @ Wf1^T + bf1) =====
// M=16384, N=128, K=384; same BK=32/16KB/2-barrier structure as gemm_bf16.
__global__ __launch_bounds__(256) void gemm_f1g(
    const int* __restrict__ inputs, const bf16_t* __restrict__ h2,
    const bf16_t* __restrict__ x3, const bf16_t* __restrict__ Wf1b,
    const float* __restrict__ bf1, bf16_t* __restrict__ f1)
{
    __shared__ char smem[16384];
    const int tid = threadIdx.x;
    const int nwg = gridDim.x;            // 128 (%8==0)
    const int q8n = nwg >> 3;
    const int xcd = blockIdx.x & 7, li = blockIdx.x >> 3;
    const int wgid = xcd * q8n + li;
    const int row0 = wgid * 128;
    const int lane = tid & 63, wv = tid >> 6;

    const int srow = lane >> 2;
    const int gchunk = (lane & 3) ^ ((lane >> 3) & 3);
    const bf16_t* baseA0[3];
    const bf16_t* baseA1[3];
    const bf16_t *pb0, *pb1;
    {
        int r0 = (wv * 2 + 0) * 16 + srow;
        int r1 = (wv * 2 + 1) * 16 + srow;
        int ar0 = row0 + r0;
        int ar1 = row0 + r1;
        int d10 = inputs[ar0 * 3 + 0], d20 = inputs[ar0 * 3 + 1];
        int d11 = inputs[ar1 * 3 + 0], d21 = inputs[ar1 * 3 + 1];
        baseA0[0] = h2 + (size_t)d10 * 128 + gchunk * 8;
        baseA0[1] = h2 + (size_t)d20 * 128 + gchunk * 8;
        baseA0[2] = x3 + (size_t)ar0 * 128 + gchunk * 8;
        baseA1[0] = h2 + (size_t)d11 * 128 + gchunk * 8;
        baseA1[1] = h2 + (size_t)d21 * 128 + gchunk * 8;
        baseA1[2] = x3 + (size_t)ar1 * 128 + gchunk * 8;
        pb0 = Wf1b + (size_t)r0 * 384 + gchunk * 8;
        pb1 = Wf1b + (size_t)r1 * 384 + gchunk * 8;
    }
    char* As = smem;
    char* Bs = smem + 8192;
    char* lA0 = As + (wv * 2 + 0) * 1024;
    char* lA1 = As + (wv * 2 + 1) * 1024;
    char* lB0 = Bs + (wv * 2 + 0) * 1024;
    char* lB1 = Bs + (wv * 2 + 1) * 1024;

    const int wm = wv >> 1, wn = wv & 1;
    const int r16 = lane & 15, kch = lane >> 4;
    const int slot = (kch ^ ((r16 >> 1) & 3)) << 4;

    f32x4 acc[4][4];
#pragma unroll
    for (int i = 0; i < 4; ++i)
#pragma unroll
        for (int j = 0; j < 4; ++j) acc[i][j] = (f32x4){0.f, 0.f, 0.f, 0.f};

#pragma unroll
    for (int it = 0; it < 12; ++it) {
        const int k0 = it * 32;
        const int reg = k0 >> 7;          // compile-time under unroll
        const int off = k0 & 127;
        gload16(baseA0[reg] + off, lA0);
        gload16(baseA1[reg] + off, lA1);
        gload16(pb0 + k0, lB0);
        gload16(pb1 + k0, lB1);
        __syncthreads();
        bf16x8 af[4], bfm[4];
#pragma unroll
        for (int i = 0; i < 4; ++i)
            af[i] = *(const bf16x8*)(As + (wm * 64 + i * 16 + r16) * 64 + slot);
#pragma unroll
        for (int j = 0; j < 4; ++j)
            bfm[j] = *(const bf16x8*)(Bs + (wn * 64 + j * 16 + r16) * 64 + slot);
#pragma unroll
        for (int i = 0; i < 4; ++i)
#pragma unroll
            for (int j = 0; j < 4; ++j)
                acc[i][j] = __builtin_amdgcn_mfma_f32_16x16x32_bf16(af[i], bfm[j], acc[i][j], 0, 0, 0);
        __syncthreads();
    }

    const int crow0 = row0 + wm * 64;
#pragma unroll
    for (int i = 0; i < 4; ++i) {
#pragma unroll
        for (int j = 0; j < 4; ++j) {
            int col = wn * 64 + j * 16 + r16;
            float bv = bf1[col];
#pragma unroll
            for (int q = 0; q < 4; ++q) {
                int row = crow0 + i * 16 + kch * 4 + q;
                float v = fmaxf(acc[i][j][q] + bv, 0.f);
                f1[(size_t)row * 128 + col] = (bf16_t)v;
            }
        }
    }
}

// ================= head: ef gather, f2+matvec tail =================
__global__ __launch_bounds__(256) void gather_ef(
    const int* __restrict__ inputs, const float* __restrict__ ef, bf16_t* __restrict__ ef_g)
{
    int i = blockIdx.x * 256 + threadIdx.x;   // over 16384*16
    int row = i >> 4, c4 = i & 15;
    int ctx = inputs[row * 3 + 2];
    float4 v = *(const float4*)(ef + (size_t)ctx * 64 + c4 * 4);
    bf16x4 o;
    o[0] = (bf16_t)v.x; o[1] = (bf16_t)v.y; o[2] = (bf16_t)v.z; o[3] = (bf16_t)v.w;
    *(bf16x4*)(ef_g + (size_t)row * 64 + c4 * 4) = o;
}

// out[r] = dot(relu(f1[r]@Wf2^T + bf2), Wf3) + bf3 ; lane = output unit (64)
__global__ __launch_bounds__(256) void head_tail(
    const bf16_t* __restrict__ f1, const bf16_t* __restrict__ Wf2b,
    const float* __restrict__ bf2, const float* __restrict__ Wf3,
    const float* __restrict__ bf3, float* __restrict__ out)
{
    __shared__ bf16_t sf1[128 * 128];   // 32 KB
    int blk = blockIdx.x;               // 128 blocks x 128 rows
    int tid = threadIdx.x;
    const bf16_t* gsrc = f1 + (size_t)blk * 128 * 128;
    for (int i = tid; i < 128 * 16; i += 256)
        ((bf16x8*)sf1)[i] = ((const bf16x8*)gsrc)[i];
    int lane = tid & 63, wv = tid >> 6;
    bf16x8 w[16];
#pragma unroll
    for (int c = 0; c < 16; ++c) w[c] = ((const bf16x8*)(Wf2b + lane * 128))[c];
    float bias2 = bf2[lane];
    float wf3 = Wf3[lane];
    float b3 = bf3[0];
    __syncthreads();
    for (int r = wv; r < 128; r += 4) {
        const bf16x8* frow = (const bf16x8*)(sf1 + r * 128);
        float acc = 0.f;
#pragma unroll
        for (int c = 0; c < 16; ++c) {
            bf16x8 fv = frow[c];
#pragma unroll
            for (int j = 0; j < 8; ++j) acc += (float)fv[j] * (float)w[c][j];
        }
        float v = fmaxf(acc + bias2, 0.f) * wf3;
#pragma unroll
        for (int off = 32; off > 0; off >>= 1) v += __shfl_down(v, off);
        if (lane == 0) out[blk * 128 + r] = v + b3;
    }
}

extern "C" void kernel_launch(void* const* d_in, const int* in_sizes, int n_in,
                              void* d_out, int out_size, void* d_ws, size_t ws_size,
                              hipStream_t stream)
{
    const int*   inputs       = (const int*)  d_in[0];
    const float* node_feature = (const float*)d_in[1];
    const float* edge_feature = (const float*)d_in[2];
    const int*   edge_src     = (const int*)  d_in[3];
    const int*   edge_dst     = (const int*)  d_in[4];
    const int*   edge_rel     = (const int*)  d_in[5];
    const float* We1 = (const float*)d_in[6];
    const float* be1 = (const float*)d_in[7];
    const float* Wl1 = (const float*)d_in[8];
    const float* bl1 = (const float*)d_in[9];
    const float* Ws1 = (const float*)d_in[10];
    const float* bs1 = (const float*)d_in[11];
    const float* We2 = (const float*)d_in[12];
    const float* be2 = (const float*)d_in[13];
    const float* Wl2 = (const float*)d_in[14];
    const float* bl2 = (const float*)d_in[15];
    const float* Ws2 = (const float*)d_in[16];
    const float* bs2 = (const float*)d_in[17];
    const float* Wc1 = (const float*)d_in[18];
    const float* bc1 = (const float*)d_in[19];
    const float* Wc2 = (const float*)d_in[20];
    const float* bc2 = (const float*)d_in[21];
    const float* Wf1 = (const float*)d_in[22];
    const float* bf1 = (const float*)d_in[23];
    const float* Wf2 = (const float*)d_in[24];
    const float* bf2 = (const float*)d_in[25];
    const float* Wf3 = (const float*)d_in[26];
    const float* bf3 = (const float*)d_in[27];
    float* out = (float*)d_out;

    // ---- workspace layout (256B aligned chunks) ----
    char* p = (char*)d_ws;
    auto alloc = [&](size_t bytes) { char* r = p; p += (bytes + 255) & ~(size_t)255; return r; };
    int* hist     = (int*)alloc(NSEG * 4);
    int* offs     = (int*)alloc(NSEG * 4);
    int* cursor   = (int*)alloc(NSEG * 4);
    int* csr_src  = (int*)alloc(N_EDGES * 4);
    int* csr_eid  = (int*)alloc(N_EDGES * 4);
    int* bsums    = (int*)alloc(128 * 4);
    bf16_t* A1    = (bf16_t*)alloc((size_t)N_NODES * K1 * 2);
    bf16_t* A2    = (bf16_t*)alloc((size_t)N_NODES * K2 * 2);
    bf16_t* xb    = (bf16_t*)alloc((size_t)N_NODES * 256 * 2);
    bf16_t* Pbuf  = (bf16_t*)alloc((size_t)N_NODES * HID * 2);
    float*  h2base= (float*)alloc((size_t)N_NODES * 128 * 4);
    bf16_t* h2    = (bf16_t*)alloc((size_t)N_NODES * 128 * 2);
    bf16_t* W1cat = (bf16_t*)alloc((size_t)512 * K1 * 2);
    bf16_t* W2cat = (bf16_t*)alloc((size_t)128 * K2 * 2);
    bf16_t* W2p   = (bf16_t*)alloc((size_t)512 * 512 * 2);
    bf16_t* Wc1b  = (bf16_t*)alloc(256 * 64 * 2);
    bf16_t* Wc2b  = (bf16_t*)alloc(128 * 256 * 2);
    bf16_t* Wf1b  = (bf16_t*)alloc(128 * 384 * 2);
    bf16_t* Wf2b  = (bf16_t*)alloc(64 * 128 * 2);
    float*  bias12= (float*)alloc(512 * 4);
    float*  bias22= (float*)alloc(128 * 4);
    bf16_t* ef_g  = (bf16_t*)alloc((size_t)BATCH * 64 * 2);
    bf16_t* u3    = (bf16_t*)alloc((size_t)BATCH * 256 * 2);
    bf16_t* x3buf = (bf16_t*)alloc((size_t)BATCH * 128 * 2);
    bf16_t* f1    = (bf16_t*)alloc((size_t)BATCH * 128 * 2);

    // ---- CSR build ----
    hipMemsetAsync(hist, 0, NSEG * 4, stream);
    hist_kernel<<<(N_EDGES + 255) / 256, 256, 0, stream>>>(edge_dst, edge_rel, hist);
    int nscan = (NSEG + SCAN_B - 1) / SCAN_B;
    scan1<<<nscan, 256, 0, stream>>>(hist, offs, bsums, NSEG);
    scan2<<<1, 64, 0, stream>>>(bsums, nscan);
    scan3<<<nscan, 256, 0, stream>>>(offs, cursor, bsums, NSEG);
    csr_fill<<<(N_EDGES + 255) / 256, 256, 0, stream>>>(edge_dst, edge_rel, edge_src,
                                                        cursor, csr_src, csr_eid);

    // ---- weight prep + converts ----
    prep_w1cat<<<512, 256, 0, stream>>>(Wl1, We1, Ws1, be1, W1cat);
    prep_w2cat<<<128, 256, 0, stream>>>(Wl2, We2, Ws2, be2, W2cat);
    prep_w2p<<<(512 * 512) / 256, 256, 0, stream>>>(Wl2, W2p);
    prep_small<<<(26624 + 640 + 255) / 256, 256, 0, stream>>>(
        Wc1, Wc2, Wf1, Wf2, bl1, bs1, bl2, bs2,
        Wc1b, Wc2b, Wf1b, Wf2b, bias12, bias22);
    xconv_k<<<(N_NODES * 64 + 255) / 256, 256, 0, stream>>>(node_feature, A1, xb);

    // ---- layer 1 ----
    agg1<<<N_NODES, 256, 0, stream>>>(edge_feature, xb, csr_src, csr_eid, offs, hist, A1, A2);
    {   // h1 = relu(A1 @ W1cat^T + bias12) -> A2 cols 256..767
        int nrow = (N_NODES + 127) / 128, ncol = HID / 128;
        gemm_bf16<1, 0, 1><<<nrow * ncol, 256, 0, stream>>>(A1, K1, W1cat, K1, nullptr, 0, bias12,
                                                            A2 + 256, K2, N_NODES, HID, K1, ncol);
    }

    // ---- layer 2 ----
    {   // P = h1 @ W2p^T
        int nrow = (N_NODES + 127) / 128, ncol = HID / 128;
        gemm_bf16<0, 0, 1><<<nrow * ncol, 256, 0, stream>>>(A2 + 256, K2, W2p, 512, nullptr, 0, nullptr,
                                                            Pbuf, HID, N_NODES, HID, 512, ncol);
    }
    agg2<<<N_NODES, 256, 0, stream>>>(Pbuf, csr_src, offs, hist, h2base);
    {   // h2 = relu(h2base + A2 @ W2cat^T + bias22)
        int nrow = (N_NODES + 127) / 128;
        gemm_bf16<1, 1, 1><<<nrow, 256, 0, stream>>>(A2, K2, W2cat, K2, h2base, 128, bias22,
                                                     h2, 128, N_NODES, 128, K2, 1);
    }

    // ---- head ----
    gather_ef<<<(BATCH * 16) / 256, 256, 0, stream>>>(inputs, edge_feature, ef_g);
    {   // u3 = relu(ef_g @ Wc1^T + bc1)
        gemm_bf16<1, 0, 1><<<(BATCH / 128) * 2, 256, 0, stream>>>(ef_g, 64, Wc1b, 64, nullptr, 0, bc1,
                                                                  u3, 256, BATCH, 256, 64, 2);
    }
    {   // x3 = u3 @ Wc2^T + bc2   (compact [16384,128])
        gemm_bf16<0, 0, 1><<<BATCH / 128, 256, 0, stream>>>(u3, 256, Wc2b, 256, nullptr, 0, bc2,
                                                            x3buf, 128, BATCH, 128, 256, 1);
    }
    // f1 = relu([h2[d1] | h2[d2] | x3] @ Wf1^T + bf1)  (gathered A)
    gemm_f1g<<<BATCH / 128, 256, 0, stream>>>(inputs, h2, x3buf, Wf1b, bf1, f1);
    // out = dot(relu(f1 @ Wf2^T + bf2), Wf3) + bf3
    head_tail<<<BATCH / 128, 256, 0, stream>>>(f1, Wf2b, bf2, Wf3, bf3, out);
}

// Round 12
// 692.196 us; speedup vs baseline: 1.0807x; 1.0807x over previous
//
#include <hip/hip_runtime.h>
#include <hip/hip_bf16.h>

#define N_NODES 50000
#define N_EDGES 800000
#define NODE_DIM 256
#define EDGE_DIM 64
#define NUM_REL 4
#define HID 512
#define LAST 128
#define BATCH 16384
#define EPS 1e-10f
#define NSEG (N_NODES * NUM_REL)

#define K1 1600   // meanX 1024 | E1 256 | x 256 | f 4 | pad 60
#define K2 832    // E1 256 | h1 512 | f 4 | pad 60

typedef __bf16 bf16_t;
typedef __attribute__((ext_vector_type(8))) __bf16 bf16x8;
typedef __attribute__((ext_vector_type(4))) __bf16 bf16x4;
typedef __attribute__((ext_vector_type(2))) __bf16 bf16x2;
typedef __attribute__((ext_vector_type(4))) float f32x4;

typedef __attribute__((address_space(1))) const unsigned int g_u32;
typedef __attribute__((address_space(3))) unsigned int l_u32;
static __device__ __forceinline__ void gload16(const void* g, void* l) {
    __builtin_amdgcn_global_load_lds((g_u32*)g, (l_u32*)l, 16, 0, 0);
}

// ================= CSR build =================
__global__ __launch_bounds__(256) void hist_kernel(
    const int* __restrict__ edst, const int* __restrict__ erel, int* __restrict__ hist)
{
    int e = blockIdx.x * 256 + threadIdx.x;
    if (e >= N_EDGES) return;
    atomicAdd(&hist[edst[e] * NUM_REL + erel[e]], 1);
}

#define SCAN_B 2048
__global__ __launch_bounds__(256) void scan1(
    const int* __restrict__ in, int* __restrict__ out, int* __restrict__ bsum, int n)
{
    __shared__ int sh[256];
    int base = blockIdx.x * SCAN_B + threadIdx.x * 8;
    int v[8]; int s = 0;
#pragma unroll
    for (int i = 0; i < 8; ++i) {
        int idx = base + i;
        v[i] = s;
        s += (idx < n) ? in[idx] : 0;
    }
    sh[threadIdx.x] = s;
    __syncthreads();
    for (int off = 1; off < 256; off <<= 1) {
        int t = (threadIdx.x >= off) ? sh[threadIdx.x - off] : 0;
        __syncthreads();
        sh[threadIdx.x] += t;
        __syncthreads();
    }
    int texcl = (threadIdx.x == 0) ? 0 : sh[threadIdx.x - 1];
#pragma unroll
    for (int i = 0; i < 8; ++i) {
        int idx = base + i;
        if (idx < n) out[idx] = texcl + v[i];
    }
    if (threadIdx.x == 255) bsum[blockIdx.x] = sh[255];
}

__global__ void scan2(int* bsum, int nb)
{
    if (threadIdx.x == 0 && blockIdx.x == 0) {
        int s = 0;
        for (int i = 0; i < nb; ++i) { int t = bsum[i]; bsum[i] = s; s += t; }
    }
}

__global__ __launch_bounds__(256) void scan3(int* __restrict__ out, int* __restrict__ cursor,
                                             const int* __restrict__ bsum, int n)
{
    int idx = blockIdx.x * SCAN_B + threadIdx.x * 8;
    int add = bsum[blockIdx.x];
#pragma unroll
    for (int i = 0; i < 8; ++i)
        if (idx + i < n) {
            int v = out[idx + i] + add;
            out[idx + i] = v;
            cursor[idx + i] = v;
        }
}

__global__ __launch_bounds__(256) void csr_fill(
    const int* __restrict__ edst, const int* __restrict__ erel, const int* __restrict__ esrc,
    int* __restrict__ cursor,
    int* __restrict__ csr_src, int* __restrict__ csr_eid)
{
    int e = blockIdx.x * 256 + threadIdx.x;
    if (e >= N_EDGES) return;
    int seg = edst[e] * NUM_REL + erel[e];
    int pos = atomicAdd(&cursor[seg], 1);
    csr_src[pos] = esrc[e];
    csr_eid[pos] = e;
}

// ================= small converts, fused =================
__global__ __launch_bounds__(256) void prep_small(
    const float* __restrict__ Wc1, const float* __restrict__ Wc2,
    const float* __restrict__ Wf1, const float* __restrict__ Wf2,
    const float* __restrict__ bl1, const float* __restrict__ bs1,
    const float* __restrict__ bl2, const float* __restrict__ bs2,
    bf16_t* __restrict__ Wc1b, bf16_t* __restrict__ Wc2b,
    bf16_t* __restrict__ Wf1b, bf16_t* __restrict__ Wf2b,
    float* __restrict__ bias12, float* __restrict__ bias22)
{
    int i = blockIdx.x * 256 + threadIdx.x;
    const float* src; bf16_t* dst; int base;
    if (i < 4096)        { src = Wc1; dst = Wc1b; base = 0; }
    else if (i < 12288)  { src = Wc2; dst = Wc2b; base = 4096; }
    else if (i < 24576)  { src = Wf1; dst = Wf1b; base = 12288; }
    else if (i < 26624)  { src = Wf2; dst = Wf2b; base = 24576; }
    else {
        int j = i - 26624;
        if (j < 512) bias12[j] = bl1[j] + bs1[j];
        else if (j < 640) bias22[j - 512] = bl2[j - 512] + bs2[j - 512];
        return;
    }
    int k = i - base;
    float4 v = ((const float4*)src)[k];
    bf16x4 o;
    o[0] = (bf16_t)v.x; o[1] = (bf16_t)v.y; o[2] = (bf16_t)v.z; o[3] = (bf16_t)v.w;
    ((bf16x4*)dst)[k] = o;
}

// x (fp32 [50000,256]) -> A1 cols 1280..1535 (bf16) AND compact xb [50000,256]
__global__ __launch_bounds__(256) void xconv_k(const float* __restrict__ x, bf16_t* __restrict__ A1,
                                               bf16_t* __restrict__ xb)
{
    int i = blockIdx.x * 256 + threadIdx.x;   // over 50000*64
    int n = i >> 6;
    int c4 = i & 63;
    float4 v = ((const float4*)(x + (size_t)n * 256))[c4];
    bf16x4 o;
    o[0] = (bf16_t)v.x; o[1] = (bf16_t)v.y; o[2] = (bf16_t)v.z; o[3] = (bf16_t)v.w;
    *(bf16x4*)(A1 + (size_t)n * K1 + 1280 + c4 * 4) = o;
    *(bf16x4*)(xb + (size_t)n * 256 + c4 * 4) = o;
}

// ================= weight prep =================
__global__ __launch_bounds__(256) void prep_w1cat(
    const float* __restrict__ Wl1, const float* __restrict__ We1,
    const float* __restrict__ Ws1, const float* __restrict__ be1, bf16_t* __restrict__ W1cat)
{
    int j = blockIdx.x;
    int t = threadIdx.x;
    const float* wrow = Wl1 + (size_t)j * 1024;
    bf16_t* out = W1cat + (size_t)j * K1;
    for (int c = t; c < 1024; c += 256) out[c] = (bf16_t)wrow[c];
    {
        int r = t >> 6, e = t & 63;
        float s = 0.f;
        const float* wr = wrow + r * 256;
        for (int c = 0; c < 256; ++c) s += wr[c] * We1[c * 64 + e];
        out[1024 + t] = (bf16_t)s;
    }
    if (t < 256) out[1280 + t] = (bf16_t)Ws1[(size_t)j * 256 + t];
    if (t < 4) {
        float s = 0.f;
        const float* wr = wrow + t * 256;
        for (int c = 0; c < 256; ++c) s += wr[c] * be1[c];
        out[1536 + t] = (bf16_t)s;
    }
    if (t >= 4 && t < 64) out[1536 + t] = (bf16_t)0.f;   // pad to K1=1600
}

__global__ __launch_bounds__(256) void prep_w2cat(
    const float* __restrict__ Wl2, const float* __restrict__ We2,
    const float* __restrict__ Ws2, const float* __restrict__ be2, bf16_t* __restrict__ W2cat)
{
    int j = blockIdx.x;
    int t = threadIdx.x;
    const float* wrow = Wl2 + (size_t)j * 2048;
    bf16_t* out = W2cat + (size_t)j * K2;
    {
        int r = t >> 6, e = t & 63;
        float s = 0.f;
        const float* wr = wrow + r * 512;
        for (int k = 0; k < 512; ++k) s += wr[k] * We2[k * 64 + e];
        out[t] = (bf16_t)s;
    }
    for (int c = t; c < 512; c += 256) out[256 + c] = (bf16_t)Ws2[(size_t)j * 512 + c];
    if (t < 4) {
        float s = 0.f;
        const float* wr = wrow + t * 512;
        for (int k = 0; k < 512; ++k) s += wr[k] * be2[k];
        out[768 + t] = (bf16_t)s;
    }
    if (t >= 4 && t < 64) out[768 + t] = (bf16_t)0.f;    // pad to K2=832
}

__global__ __launch_bounds__(256) void prep_w2p(const float* __restrict__ Wl2, bf16_t* __restrict__ W2p)
{
    int idx = blockIdx.x * 256 + threadIdx.x;    // 512*512
    int row = idx >> 9, k = idx & 511;
    int j = row & 127, r = row >> 7;
    W2p[idx] = (bf16_t)Wl2[(size_t)j * 2048 + r * 512 + k];
}

// ================= aggregation =================
__global__ __launch_bounds__(256) void agg1(
    const float* __restrict__ ef, const bf16_t* __restrict__ xb,
    const int* __restrict__ csr_src, const int* __restrict__ csr_eid,
    const int* __restrict__ offs, const int* __restrict__ hist,
    bf16_t* __restrict__ A1, bf16_t* __restrict__ A2)
{
    int n = blockIdx.x;
    int w = threadIdx.x >> 6;
    int lane = threadIdx.x & 63;
    int half = lane >> 5;
    int l32 = lane & 31;
    int seg = n * NUM_REL + w;
    int beg = offs[seg], ct = hist[seg];

    float xs[8] = {0.f, 0.f, 0.f, 0.f, 0.f, 0.f, 0.f, 0.f};
    float es0 = 0.f, es1 = 0.f;

    int i = 0;
    for (; i + 4 <= ct; i += 4) {
        int sA = csr_src[beg + i + half];
        int sB = csr_src[beg + i + 2 + half];
        int eA = csr_eid[beg + i + half];
        int eB = csr_eid[beg + i + 2 + half];
        bf16x8 vA = *(const bf16x8*)(xb + (size_t)sA * 256 + l32 * 8);
        bf16x8 vB = *(const bf16x8*)(xb + (size_t)sB * 256 + l32 * 8);
        float2 fA = *(const float2*)(ef + (size_t)eA * 64 + l32 * 2);
        float2 fB = *(const float2*)(ef + (size_t)eB * 64 + l32 * 2);
#pragma unroll
        for (int j = 0; j < 8; ++j) xs[j] += (float)vA[j] + (float)vB[j];
        es0 += fA.x + fB.x;
        es1 += fA.y + fB.y;
    }
    for (; i + 2 <= ct; i += 2) {
        int sA = csr_src[beg + i + half];
        int eA = csr_eid[beg + i + half];
        bf16x8 vA = *(const bf16x8*)(xb + (size_t)sA * 256 + l32 * 8);
        float2 fA = *(const float2*)(ef + (size_t)eA * 64 + l32 * 2);
#pragma unroll
        for (int j = 0; j < 8; ++j) xs[j] += (float)vA[j];
        es0 += fA.x;
        es1 += fA.y;
    }
    if (i < ct && half == 0) {
        int sA = csr_src[beg + i];
        int eA = csr_eid[beg + i];
        bf16x8 vA = *(const bf16x8*)(xb + (size_t)sA * 256 + l32 * 8);
        float2 fA = *(const float2*)(ef + (size_t)eA * 64 + l32 * 2);
#pragma unroll
        for (int j = 0; j < 8; ++j) xs[j] += (float)vA[j];
        es0 += fA.x;
        es1 += fA.y;
    }
#pragma unroll
    for (int j = 0; j < 8; ++j) xs[j] += __shfl_xor(xs[j], 32);
    es0 += __shfl_xor(es0, 32);
    es1 += __shfl_xor(es1, 32);

    float inv = 1.0f / ((float)ct + EPS);
    if (half == 0) {
        bf16x8 m;
#pragma unroll
        for (int j = 0; j < 8; ++j) m[j] = (bf16_t)(xs[j] * inv);
        *(bf16x8*)(A1 + (size_t)n * K1 + w * 256 + l32 * 8) = m;
        bf16x2 e2;
        e2[0] = (bf16_t)(es0 * inv);
        e2[1] = (bf16_t)(es1 * inv);
        *(bf16x2*)(A1 + (size_t)n * K1 + 1024 + w * 64 + l32 * 2) = e2;
        *(bf16x2*)(A2 + (size_t)n * K2 + w * 64 + l32 * 2) = e2;
    }
    if (lane == 0) {
        bf16_t fv = (bf16_t)((float)ct * inv);
        A1[(size_t)n * K1 + 1536 + w] = fv;
        A2[(size_t)n * K2 + 768 + w] = fv;
    }
    if (w == 3 && lane >= 4) {
        A1[(size_t)n * K1 + 1536 + lane] = (bf16_t)0.f;   // 1540..1599
        A2[(size_t)n * K2 + 768 + lane] = (bf16_t)0.f;    // 772..831
    }
}

__global__ __launch_bounds__(256) void agg2(
    const bf16_t* __restrict__ P, const int* __restrict__ csr_src,
    const int* __restrict__ offs, const int* __restrict__ hist,
    float* __restrict__ h2base)
{
    __shared__ float red[4][128];
    int n = blockIdx.x;
    int w = threadIdx.x >> 6;
    int lane = threadIdx.x & 63;
    int half = lane >> 5;
    int l32 = lane & 31;
    int seg = n * NUM_REL + w;
    int beg = offs[seg], ct = hist[seg];

    float s0 = 0.f, s1 = 0.f, s2 = 0.f, s3 = 0.f;
    int i = 0;
    for (; i + 4 <= ct; i += 4) {
        int a = csr_src[beg + i + half];
        int b = csr_src[beg + i + 2 + half];
        bf16x4 va = *(const bf16x4*)(P + (size_t)a * HID + w * 128 + l32 * 4);
        bf16x4 vb = *(const bf16x4*)(P + (size_t)b * HID + w * 128 + l32 * 4);
        s0 += (float)va[0] + (float)vb[0];
        s1 += (float)va[1] + (float)vb[1];
        s2 += (float)va[2] + (float)vb[2];
        s3 += (float)va[3] + (float)vb[3];
    }
    for (; i + 2 <= ct; i += 2) {
        int a = csr_src[beg + i + half];
        bf16x4 va = *(const bf16x4*)(P + (size_t)a * HID + w * 128 + l32 * 4);
        s0 += (float)va[0]; s1 += (float)va[1]; s2 += (float)va[2]; s3 += (float)va[3];
    }
    if (i < ct && half == 0) {
        int a = csr_src[beg + i];
        bf16x4 va = *(const bf16x4*)(P + (size_t)a * HID + w * 128 + l32 * 4);
        s0 += (float)va[0]; s1 += (float)va[1]; s2 += (float)va[2]; s3 += (float)va[3];
    }
    s0 += __shfl_xor(s0, 32);
    s1 += __shfl_xor(s1, 32);
    s2 += __shfl_xor(s2, 32);
    s3 += __shfl_xor(s3, 32);

    float inv = 1.0f / ((float)ct + EPS);
    if (half == 0) {
        red[w][l32 * 4 + 0] = s0 * inv;
        red[w][l32 * 4 + 1] = s1 * inv;
        red[w][l32 * 4 + 2] = s2 * inv;
        red[w][l32 * 4 + 3] = s3 * inv;
    }
    __syncthreads();
    int t = threadIdx.x;
    if (t < 128)
        h2base[(size_t)n * 128 + t] = red[0][t] + red[1][t] + red[2][t] + red[3][t];
}

// ================= 256x256 8-wave phase-split GEMM (BK=32, triple-buffer) =====
// C = act(A[M,K]@W[N,K]^T + bias), bf16 out. 512 threads = 8 waves (2M x 4N),
// per-wave C = 128x64 (acc[8][4]). LDS: 3 bufs x (A 16KB | B 16KB) = 96KB.
// Per K-tile (BK=32): 2 phases {ds_read frags | stage half of tile t+2 |
// barrier | lgkmcnt(0)+sched_barrier | setprio(1) 16 MFMA setprio(0) | barrier}.
// Counted vmcnt(4) at tile boundary only (tile t+1's loads issued 2 tiles ago).
// Swizzle (verified r11): stage chunk (l&3)^((l>>3)&3) at slot l&3; read slot
// kch^((r16>>1)&3); <=2-way conflicts (free). Requires N%256==0, K%32==0.
template<int RELU>
__global__ __launch_bounds__(512) void gemm256(
    const bf16_t* __restrict__ A, int lda,
    const bf16_t* __restrict__ W, int ldw,
    const float* __restrict__ bias,
    bf16_t* __restrict__ Cout, int ldc,
    int M, int N, int K, int ncol)
{
    __shared__ char smem[98304];
    const int tid = threadIdx.x;

    const int nwg = gridDim.x;
    const int q8 = nwg >> 3, r8 = nwg & 7;
    const int xcd = blockIdx.x & 7, li = blockIdx.x >> 3;
    const int wgid = (xcd < r8 ? xcd * (q8 + 1) : r8 * (q8 + 1) + (xcd - r8) * q8) + li;

    const int row0 = (wgid / ncol) * 256;
    const int col0 = (wgid % ncol) * 256;
    const int lane = tid & 63, wv = tid >> 6;

    // staging: wave wv stages A row-groups g=wv*2+s and B likewise (16 rows each)
    const int rsub = lane >> 2;                       // 0..15 row in group
    const int gc = (lane & 3) ^ ((lane >> 3) & 3);    // pre-swizzled global chunk
    const bf16_t *pa[2], *pb[2];
    int lof[2];
#pragma unroll
    for (int s = 0; s < 2; ++s) {
        int g = wv * 2 + s;
        int ar = row0 + g * 16 + rsub; if (ar >= M) ar = M - 1;
        int br = col0 + g * 16 + rsub; if (br >= N) br = N - 1;
        pa[s] = A + (size_t)ar * lda + gc * 8;
        pb[s] = W + (size_t)br * ldw + gc * 8;
        lof[s] = g * 1024;
    }

    const int wm = wv >> 2, wn = wv & 3;
    const int r16 = lane & 15, kch = lane >> 4;
    const int slot = (kch ^ ((r16 >> 1) & 3)) << 4;

    f32x4 acc[8][4];
#pragma unroll
    for (int i = 0; i < 8; ++i)
#pragma unroll
        for (int j = 0; j < 4; ++j) acc[i][j] = (f32x4){0.f, 0.f, 0.f, 0.f};

    const int nt = K >> 5;
    // prologue: stage tiles 0 and 1
#pragma unroll
    for (int t = 0; t < 2; ++t) {
        char* b = smem + t * 32768;
        gload16(pa[0] + t * 32, b + lof[0]);
        gload16(pa[1] + t * 32, b + lof[1]);
        gload16(pb[0] + t * 32, b + 16384 + lof[0]);
        gload16(pb[1] + t * 32, b + 16384 + lof[1]);
    }
    asm volatile("s_waitcnt vmcnt(4)" ::: "memory");
    __builtin_amdgcn_s_barrier();

    for (int t = 0; t < nt; ++t) {
        char* buf = smem + (t % 3) * 32768;
        char* nbuf = smem + ((t + 2) % 3) * 32768;
        const bool st = (t + 2 < nt);
        const int k2 = (t + 2) * 32;

        // ---- phase 0: rows wm*128 + 0..63 ----
        bf16x8 bA[4], bB[4];
#pragma unroll
        for (int i = 0; i < 4; ++i)
            bA[i] = *(const bf16x8*)(buf + (wm * 128 + i * 16 + r16) * 64 + slot);
#pragma unroll
        for (int j = 0; j < 4; ++j)
            bB[j] = *(const bf16x8*)(buf + 16384 + (wn * 64 + j * 16 + r16) * 64 + slot);
        if (st) {
            gload16(pa[0] + k2, nbuf + lof[0]);
            gload16(pa[1] + k2, nbuf + lof[1]);
        }
        __builtin_amdgcn_s_barrier();
        asm volatile("s_waitcnt lgkmcnt(0)" ::: "memory");
        __builtin_amdgcn_sched_barrier(0);
        __builtin_amdgcn_s_setprio(1);
#pragma unroll
        for (int i = 0; i < 4; ++i)
#pragma unroll
            for (int j = 0; j < 4; ++j)
                acc[i][j] = __builtin_amdgcn_mfma_f32_16x16x32_bf16(bA[i], bB[j], acc[i][j], 0, 0, 0);
        __builtin_amdgcn_s_setprio(0);
        __builtin_amdgcn_s_barrier();

        // ---- phase 1: rows wm*128 + 64..127 ----
        bf16x8 aH[4];
#pragma unroll
        for (int i = 0; i < 4; ++i)
            aH[i] = *(const bf16x8*)(buf + (wm * 128 + 64 + i * 16 + r16) * 64 + slot);
        if (st) {
            gload16(pb[0] + k2, nbuf + 16384 + lof[0]);
            gload16(pb[1] + k2, nbuf + 16384 + lof[1]);
        }
        __builtin_amdgcn_s_barrier();
        asm volatile("s_waitcnt lgkmcnt(0)" ::: "memory");
        __builtin_amdgcn_sched_barrier(0);
        __builtin_amdgcn_s_setprio(1);
#pragma unroll
        for (int i = 0; i < 4; ++i)
#pragma unroll
            for (int j = 0; j < 4; ++j)
                acc[4 + i][j] = __builtin_amdgcn_mfma_f32_16x16x32_bf16(aH[i], bB[j], acc[4 + i][j], 0, 0, 0);
        __builtin_amdgcn_s_setprio(0);
        if (t + 1 < nt) {
            if (st) asm volatile("s_waitcnt vmcnt(4)" ::: "memory");
            else    asm volatile("s_waitcnt vmcnt(0)" ::: "memory");
        }
        __builtin_amdgcn_s_barrier();
    }

    // ---- epilogue ----
    const int crow0 = row0 + wm * 128;
#pragma unroll
    for (int i = 0; i < 8; ++i) {
#pragma unroll
        for (int j = 0; j < 4; ++j) {
            int col = col0 + wn * 64 + j * 16 + r16;
            float bv = bias ? bias[col] : 0.f;
#pragma unroll
            for (int q = 0; q < 4; ++q) {
                int row = crow0 + i * 16 + kch * 4 + q;
                if (row >= M) continue;
                float v = acc[i][j][q] + bv;
                if (RELU) v = fmaxf(v, 0.f);
                Cout[(size_t)row * ldc + col] = (bf16_t)v;
            }
        }
    }
}

// ================= 128x128 dbuf GEMM (round-9/10 structure, small GEMMs) ======
template<int RELU, int ACC, int OUTBF>
__global__ __launch_bounds__(256) void gemm_bf16(
    const bf16_t* __restrict__ A, int lda,
    const bf16_t* __restrict__ W, int ldw,
    const float* __restrict__ Cin, int ldcin,
    const float* __restrict__ bias,
    void* __restrict__ Cout, int ldc,
    int M, int N, int K, int ncol)
{
    __shared__ char smem[65536];
    const int tid = threadIdx.x;

    const int nwg = gridDim.x;
    const int q8 = nwg >> 3, r8 = nwg & 7;
    const int xcd = blockIdx.x & 7, li = blockIdx.x >> 3;
    const int wgid = (xcd < r8 ? xcd * (q8 + 1) : r8 * (q8 + 1) + (xcd - r8) * q8) + li;

    const int row0 = (wgid / ncol) * 128;
    const int col0 = (wgid % ncol) * 128;
    const int lane = tid & 63, wv = tid >> 6;

    const int rsub = lane >> 3;
    const int gchunk = (lane & 7) ^ rsub;
    const bf16_t* pa[4]; const bf16_t* pb[4];
    int lofs[4];
#pragma unroll
    for (int s = 0; s < 4; ++s) {
        int q = wv * 4 + s;
        int ar = row0 + q * 8 + rsub; if (ar >= M) ar = M - 1;
        int br = col0 + q * 8 + rsub; if (br >= N) br = N - 1;
        pa[s] = A + (size_t)ar * lda + gchunk * 8;
        pb[s] = W + (size_t)br * ldw + gchunk * 8;
        lofs[s] = q * 1024;
    }

    const int wm = wv >> 1, wn = wv & 1;
    const int r16 = lane & 15, kch = lane >> 4;
    const int sw = r16 & 7;

    f32x4 acc[4][4];
#pragma unroll
    for (int i = 0; i < 4; ++i)
#pragma unroll
        for (int j = 0; j < 4; ++j) acc[i][j] = (f32x4){0.f, 0.f, 0.f, 0.f};

#pragma unroll
    for (int s = 0; s < 4; ++s) {
        gload16(pa[s], smem + lofs[s]);
        gload16(pb[s], smem + 16384 + lofs[s]);
    }

    const int nk = K >> 6;
    int cur = 0;
    for (int it = 0; it < nk; ++it) {
        const int k0 = it << 6;
        if (it + 1 < nk) {
            char* nb = smem + ((cur ^ 1) << 15);
#pragma unroll
            for (int s = 0; s < 4; ++s) {
                gload16(pa[s] + k0 + 64, nb + lofs[s]);
                gload16(pb[s] + k0 + 64, nb + 16384 + lofs[s]);
            }
            asm volatile("s_waitcnt vmcnt(8)" ::: "memory");
        } else {
            asm volatile("s_waitcnt vmcnt(0)" ::: "memory");
        }
        __builtin_amdgcn_s_barrier();
        __builtin_amdgcn_sched_barrier(0);
        const char* As = smem + (cur << 15);
        const char* Bs = As + 16384;
#pragma unroll
        for (int t = 0; t < 2; ++t) {
            const int slot = ((t * 4 + kch) ^ sw) << 4;
            bf16x8 af[4], bfm[4];
#pragma unroll
            for (int i = 0; i < 4; ++i)
                af[i] = *(const bf16x8*)(As + (wm * 64 + i * 16 + r16) * 128 + slot);
#pragma unroll
            for (int j = 0; j < 4; ++j)
                bfm[j] = *(const bf16x8*)(Bs + (wn * 64 + j * 16 + r16) * 128 + slot);
#pragma unroll
            for (int i = 0; i < 4; ++i)
#pragma unroll
                for (int j = 0; j < 4; ++j)
                    acc[i][j] = __builtin_amdgcn_mfma_f32_16x16x32_bf16(af[i], bfm[j], acc[i][j], 0, 0, 0);
        }
        __builtin_amdgcn_s_barrier();
        cur ^= 1;
    }

    const int crow0 = row0 + wm * 64;
#pragma unroll
    for (int i = 0; i < 4; ++i) {
#pragma unroll
        for (int j = 0; j < 4; ++j) {
            int col = col0 + wn * 64 + j * 16 + r16;
            if (col >= N) continue;
            float bv = bias ? bias[col] : 0.f;
#pragma unroll
            for (int q = 0; q < 4; ++q) {
                int row = crow0 + i * 16 + kch * 4 + q;
                if (row >= M) continue;
                float v = acc[i][j][q] + bv;
                if (ACC) v += Cin[(size_t)row * ldcin + col];
                if (RELU) v = fmaxf(v, 0.f);
                if (OUTBF) ((bf16_t*)Cout)[(size_t)row * ldc + col] = (bf16_t)v;
                else       ((float*)Cout)[(size_t)row * ldc + col] = v;
            }
        }
    }
}

// ======== gathered-A f1 GEMM ========
__global__ __launch_bounds__(256) void gemm_f1g(
    const int* __restrict__ inputs, const bf16_t* __restrict__ h2,
    const bf16_t* __restrict__ x3, const bf16_t* __restrict__ Wf1b,
    const float* __restrict__ bf1, bf16_t* __restrict__ f1)
{
    __shared__ char smem[65536];
    const int tid = threadIdx.x;
    const int nwg = gridDim.x;            // 128 (%8==0)
    const int q8 = nwg >> 3;
    const int xcd = blockIdx.x & 7, li = blockIdx.x >> 3;
    const int wgid = xcd * q8 + li;
    const int row0 = wgid * 128;
    const int lane = tid & 63, wv = tid >> 6;

    const int rsub = lane >> 3;
    const int gchunk = (lane & 7) ^ rsub;
    const bf16_t* baseA[4][3];
    const bf16_t* pb[4];
    int lofs[4];
#pragma unroll
    for (int s = 0; s < 4; ++s) {
        int q = wv * 4 + s;
        int ar = row0 + q * 8 + rsub;
        int d1 = inputs[ar * 3 + 0];
        int d2 = inputs[ar * 3 + 1];
        baseA[s][0] = h2 + (size_t)d1 * 128 + gchunk * 8;
        baseA[s][1] = h2 + (size_t)d2 * 128 + gchunk * 8;
        baseA[s][2] = x3 + (size_t)ar * 128 + gchunk * 8;
        int br = q * 8 + rsub;
        pb[s] = Wf1b + (size_t)br * 384 + gchunk * 8;
        lofs[s] = q * 1024;
    }

    const int wm = wv >> 1, wn = wv & 1;
    const int r16 = lane & 15, kch = lane >> 4;
    const int sw = r16 & 7;

    f32x4 acc[4][4];
#pragma unroll
    for (int i = 0; i < 4; ++i)
#pragma unroll
        for (int j = 0; j < 4; ++j) acc[i][j] = (f32x4){0.f, 0.f, 0.f, 0.f};

#pragma unroll
    for (int s = 0; s < 4; ++s) {
        gload16(baseA[s][0], smem + lofs[s]);
        gload16(pb[s], smem + 16384 + lofs[s]);
    }

    int cur = 0;
#pragma unroll
    for (int it = 0; it < 6; ++it) {
        const int k0 = it << 6;
        if (it < 5) {
            const int kn = k0 + 64;
            const int reg = kn >> 7, off = kn & 127;
            char* nb = smem + ((cur ^ 1) << 15);
#pragma unroll
            for (int s = 0; s < 4; ++s) {
                gload16(baseA[s][reg] + off, nb + lofs[s]);
                gload16(pb[s] + kn, nb + 16384 + lofs[s]);
            }
            asm volatile("s_waitcnt vmcnt(8)" ::: "memory");
        } else {
            asm volatile("s_waitcnt vmcnt(0)" ::: "memory");
        }
        __builtin_amdgcn_s_barrier();
        __builtin_amdgcn_sched_barrier(0);
        const char* As = smem + (cur << 15);
        const char* Bs = As + 16384;
#pragma unroll
        for (int t = 0; t < 2; ++t) {
            const int slot = ((t * 4 + kch) ^ sw) << 4;
            bf16x8 af[4], bfm[4];
#pragma unroll
            for (int i = 0; i < 4; ++i)
                af[i] = *(const bf16x8*)(As + (wm * 64 + i * 16 + r16) * 128 + slot);
#pragma unroll
            for (int j = 0; j < 4; ++j)
                bfm[j] = *(const bf16x8*)(Bs + (wn * 64 + j * 16 + r16) * 128 + slot);
#pragma unroll
            for (int i = 0; i < 4; ++i)
#pragma unroll
                for (int j = 0; j < 4; ++j)
                    acc[i][j] = __builtin_amdgcn_mfma_f32_16x16x32_bf16(af[i], bfm[j], acc[i][j], 0, 0, 0);
        }
        __builtin_amdgcn_s_barrier();
        cur ^= 1;
    }

    const int crow0 = row0 + wm * 64;
#pragma unroll
    for (int i = 0; i < 4; ++i) {
#pragma unroll
        for (int j = 0; j < 4; ++j) {
            int col = wn * 64 + j * 16 + r16;
            float bv = bf1[col];
#pragma unroll
            for (int q = 0; q < 4; ++q) {
                int row = crow0 + i * 16 + kch * 4 + q;
                float v = fmaxf(acc[i][j][q] + bv, 0.f);
                f1[(size_t)row * 128 + col] = (bf16_t)v;
            }
        }
    }
}

// ================= head: ef gather, f2+matvec tail =================
__global__ __launch_bounds__(256) void gather_ef(
    const int* __restrict__ inputs, const float* __restrict__ ef, bf16_t* __restrict__ ef_g)
{
    int i = blockIdx.x * 256 + threadIdx.x;   // over 16384*16
    int row = i >> 4, c4 = i & 15;
    int ctx = inputs[row * 3 + 2];
    float4 v = *(const float4*)(ef + (size_t)ctx * 64 + c4 * 4);
    bf16x4 o;
    o[0] = (bf16_t)v.x; o[1] = (bf16_t)v.y; o[2] = (bf16_t)v.z; o[3] = (bf16_t)v.w;
    *(bf16x4*)(ef_g + (size_t)row * 64 + c4 * 4) = o;
}

__global__ __launch_bounds__(256) void head_tail(
    const bf16_t* __restrict__ f1, const bf16_t* __restrict__ Wf2b,
    const float* __restrict__ bf2, const float* __restrict__ Wf3,
    const float* __restrict__ bf3, float* __restrict__ out)
{
    __shared__ bf16_t sf1[128 * 128];
    int blk = blockIdx.x;
    int tid = threadIdx.x;
    const bf16_t* gsrc = f1 + (size_t)blk * 128 * 128;
    for (int i = tid; i < 128 * 16; i += 256)
        ((bf16x8*)sf1)[i] = ((const bf16x8*)gsrc)[i];
    int lane = tid & 63, wv = tid >> 6;
    bf16x8 w[16];
#pragma unroll
    for (int c = 0; c < 16; ++c) w[c] = ((const bf16x8*)(Wf2b + lane * 128))[c];
    float bias2 = bf2[lane];
    float wf3 = Wf3[lane];
    float b3 = bf3[0];
    __syncthreads();
    for (int r = wv; r < 128; r += 4) {
        const bf16x8* frow = (const bf16x8*)(sf1 + r * 128);
        float acc = 0.f;
#pragma unroll
        for (int c = 0; c < 16; ++c) {
            bf16x8 fv = frow[c];
#pragma unroll
            for (int j = 0; j < 8; ++j) acc += (float)fv[j] * (float)w[c][j];
        }
        float v = fmaxf(acc + bias2, 0.f) * wf3;
#pragma unroll
        for (int off = 32; off > 0; off >>= 1) v += __shfl_down(v, off);
        if (lane == 0) out[blk * 128 + r] = v + b3;
    }
}

extern "C" void kernel_launch(void* const* d_in, const int* in_sizes, int n_in,
                              void* d_out, int out_size, void* d_ws, size_t ws_size,
                              hipStream_t stream)
{
    const int*   inputs       = (const int*)  d_in[0];
    const float* node_feature = (const float*)d_in[1];
    const float* edge_feature = (const float*)d_in[2];
    const int*   edge_src     = (const int*)  d_in[3];
    const int*   edge_dst     = (const int*)  d_in[4];
    const int*   edge_rel     = (const int*)  d_in[5];
    const float* We1 = (const float*)d_in[6];
    const float* be1 = (const float*)d_in[7];
    const float* Wl1 = (const float*)d_in[8];
    const float* bl1 = (const float*)d_in[9];
    const float* Ws1 = (const float*)d_in[10];
    const float* bs1 = (const float*)d_in[11];
    const float* We2 = (const float*)d_in[12];
    const float* be2 = (const float*)d_in[13];
    const float* Wl2 = (const float*)d_in[14];
    const float* bl2 = (const float*)d_in[15];
    const float* Ws2 = (const float*)d_in[16];
    const float* bs2 = (const float*)d_in[17];
    const float* Wc1 = (const float*)d_in[18];
    const float* bc1 = (const float*)d_in[19];
    const float* Wc2 = (const float*)d_in[20];
    const float* bc2 = (const float*)d_in[21];
    const float* Wf1 = (const float*)d_in[22];
    const float* bf1 = (const float*)d_in[23];
    const float* Wf2 = (const float*)d_in[24];
    const float* bf2 = (const float*)d_in[25];
    const float* Wf3 = (const float*)d_in[26];
    const float* bf3 = (const float*)d_in[27];
    float* out = (float*)d_out;

    // ---- workspace layout (256B aligned chunks) ----
    char* p = (char*)d_ws;
    auto alloc = [&](size_t bytes) { char* r = p; p += (bytes + 255) & ~(size_t)255; return r; };
    int* hist     = (int*)alloc(NSEG * 4);
    int* offs     = (int*)alloc(NSEG * 4);
    int* cursor   = (int*)alloc(NSEG * 4);
    int* csr_src  = (int*)alloc(N_EDGES * 4);
    int* csr_eid  = (int*)alloc(N_EDGES * 4);
    int* bsums    = (int*)alloc(128 * 4);
    bf16_t* A1    = (bf16_t*)alloc((size_t)N_NODES * K1 * 2);
    bf16_t* A2    = (bf16_t*)alloc((size_t)N_NODES * K2 * 2);
    bf16_t* xb    = (bf16_t*)alloc((size_t)N_NODES * 256 * 2);
    bf16_t* Pbuf  = (bf16_t*)alloc((size_t)N_NODES * HID * 2);
    float*  h2base= (float*)alloc((size_t)N_NODES * 128 * 4);
    bf16_t* h2    = (bf16_t*)alloc((size_t)N_NODES * 128 * 2);
    bf16_t* W1cat = (bf16_t*)alloc((size_t)512 * K1 * 2);
    bf16_t* W2cat = (bf16_t*)alloc((size_t)128 * K2 * 2);
    bf16_t* W2p   = (bf16_t*)alloc((size_t)512 * 512 * 2);
    bf16_t* Wc1b  = (bf16_t*)alloc(256 * 64 * 2);
    bf16_t* Wc2b  = (bf16_t*)alloc(128 * 256 * 2);
    bf16_t* Wf1b  = (bf16_t*)alloc(128 * 384 * 2);
    bf16_t* Wf2b  = (bf16_t*)alloc(64 * 128 * 2);
    float*  bias12= (float*)alloc(512 * 4);
    float*  bias22= (float*)alloc(128 * 4);
    bf16_t* ef_g  = (bf16_t*)alloc((size_t)BATCH * 64 * 2);
    bf16_t* u3    = (bf16_t*)alloc((size_t)BATCH * 256 * 2);
    bf16_t* x3buf = (bf16_t*)alloc((size_t)BATCH * 128 * 2);
    bf16_t* f1    = (bf16_t*)alloc((size_t)BATCH * 128 * 2);

    // ---- CSR build ----
    hipMemsetAsync(hist, 0, NSEG * 4, stream);
    hist_kernel<<<(N_EDGES + 255) / 256, 256, 0, stream>>>(edge_dst, edge_rel, hist);
    int nscan = (NSEG + SCAN_B - 1) / SCAN_B;
    scan1<<<nscan, 256, 0, stream>>>(hist, offs, bsums, NSEG);
    scan2<<<1, 64, 0, stream>>>(bsums, nscan);
    scan3<<<nscan, 256, 0, stream>>>(offs, cursor, bsums, NSEG);
    csr_fill<<<(N_EDGES + 255) / 256, 256, 0, stream>>>(edge_dst, edge_rel, edge_src,
                                                        cursor, csr_src, csr_eid);

    // ---- weight prep + converts ----
    prep_w1cat<<<512, 256, 0, stream>>>(Wl1, We1, Ws1, be1, W1cat);
    prep_w2cat<<<128, 256, 0, stream>>>(Wl2, We2, Ws2, be2, W2cat);
    prep_w2p<<<(512 * 512) / 256, 256, 0, stream>>>(Wl2, W2p);
    prep_small<<<(26624 + 640 + 255) / 256, 256, 0, stream>>>(
        Wc1, Wc2, Wf1, Wf2, bl1, bs1, bl2, bs2,
        Wc1b, Wc2b, Wf1b, Wf2b, bias12, bias22);
    xconv_k<<<(N_NODES * 64 + 255) / 256, 256, 0, stream>>>(node_feature, A1, xb);

    // ---- layer 1 ----
    agg1<<<N_NODES, 256, 0, stream>>>(edge_feature, xb, csr_src, csr_eid, offs, hist, A1, A2);
    {   // h1 = relu(A1 @ W1cat^T + bias12) -> A2 cols 256..767  (256^2 phase-split)
        int nrow = (N_NODES + 255) / 256, ncol = HID / 256;   // 196 x 2
        gemm256<1><<<nrow * ncol, 512, 0, stream>>>(A1, K1, W1cat, K1, bias12,
                                                    A2 + 256, K2, N_NODES, HID, K1, ncol);
    }

    // ---- layer 2 ----
    {   // P = h1 @ W2p^T  (256^2 phase-split, K=512)
        int nrow = (N_NODES + 255) / 256, ncol = HID / 256;
        gemm256<0><<<nrow * ncol, 512, 0, stream>>>(A2 + 256, K2, W2p, 512, nullptr,
                                                    Pbuf, HID, N_NODES, HID, 512, ncol);
    }
    agg2<<<N_NODES, 256, 0, stream>>>(Pbuf, csr_src, offs, hist, h2base);
    {   // h2 = relu(h2base + A2 @ W2cat^T + bias22)
        int nrow = (N_NODES + 127) / 128;
        gemm_bf16<1, 1, 1><<<nrow, 256, 0, stream>>>(A2, K2, W2cat, K2, h2base, 128, bias22,
                                                     h2, 128, N_NODES, 128, K2, 1);
    }

    // ---- head ----
    gather_ef<<<(BATCH * 16) / 256, 256, 0, stream>>>(inputs, edge_feature, ef_g);
    {   // u3 = relu(ef_g @ Wc1^T + bc1)
        gemm_bf16<1, 0, 1><<<(BATCH / 128) * 2, 256, 0, stream>>>(ef_g, 64, Wc1b, 64, nullptr, 0, bc1,
                                                                  u3, 256, BATCH, 256, 64, 2);
    }
    {   // x3 = u3 @ Wc2^T + bc2
        gemm_bf16<0, 0, 1><<<BATCH / 128, 256, 0, stream>>>(u3, 256, Wc2b, 256, nullptr, 0, bc2,
                                                            x3buf, 128, BATCH, 128, 256, 1);
    }
    gemm_f1g<<<BATCH / 128, 256, 0, stream>>>(inputs, h2, x3buf, Wf1b, bf1, f1);
    head_tail<<<BATCH / 128, 256, 0, stream>>>(f1, Wf2b, bf2, Wf3, bf3, out);
}